// Round 1
// baseline (70.037 us; speedup 1.0000x reference)
//
#include <hip/hip_runtime.h>
#include <math.h>

#define NN 512
#define DD 512
#define HH 1024
#define C2LOG2E 2.8853900817779268f   // 2*log2(e): exp(2y) = exp2(C*y)

static __device__ __forceinline__ float rcp_fast(float x) {
    return __builtin_amdgcn_rcpf(x);   // v_rcp_f32, ~1 ulp
}

// ---------------------------------------------------------------------------
// Kernel A: E[i][n], n in [0,2048).
//   n <  1024: E1 = exp2(C * (x @ W1[:D])[i,n])
//   n >= 1024: E2 = exp2(C * ((x @ W1[D:])[i,n-1024] + b1[n-1024]))
// f32 vector GEMM, 64x64 tile, BK=32, 256 threads, 4x4 micro-tile.
// ---------------------------------------------------------------------------
__global__ __launch_bounds__(256) void k_gemm_exp(const float* __restrict__ x,
                                                  const float* __restrict__ W1,
                                                  const float* __restrict__ b1,
                                                  float* __restrict__ E) {
    __shared__ float As[32][68];   // A^T tile: [k][i], pad 68 for write spread
    __shared__ float Bs[32][64];   // B tile: [k][n]
    const int t = threadIdx.x;
    const int i0g = blockIdx.x * 64;        // 8 i-tiles
    const int bn = blockIdx.y;              // 32 n-tiles over 2048
    const bool second = (bn >= 16);
    const int nglob = (second ? bn - 16 : bn) * 64;   // col within 1024
    const float* __restrict__ Wb = W1 + (second ? DD * HH : 0);
    const int tx = t & 15, ty = t >> 4;

    float acc[4][4] = {};

    for (int kt = 0; kt < DD; kt += 32) {
#pragma unroll
        for (int u = 0; u < 8; ++u) {          // stage A 64x32 (transposed)
            const int idx = t + u * 256;
            const int i = idx >> 5, k = idx & 31;
            As[k][i] = x[(i0g + i) * DD + kt + k];
        }
#pragma unroll
        for (int u = 0; u < 8; ++u) {          // stage B 32x64
            const int idx = t + u * 256;
            const int k = idx >> 6, n = idx & 63;
            Bs[k][n] = Wb[(kt + k) * HH + nglob + n];
        }
        __syncthreads();
#pragma unroll
        for (int k = 0; k < 32; ++k) {
            const float4 a = *(const float4*)&As[k][ty * 4];
            const float4 b = *(const float4*)&Bs[k][tx * 4];
            const float av[4] = {a.x, a.y, a.z, a.w};
            const float bv[4] = {b.x, b.y, b.z, b.w};
#pragma unroll
            for (int m = 0; m < 4; ++m)
#pragma unroll
                for (int n = 0; n < 4; ++n)
                    acc[m][n] = __builtin_fmaf(av[m], bv[n], acc[m][n]);
        }
        __syncthreads();
    }

    const int col = nglob + tx * 4;       // within [0,1024)
    const int ecol = bn * 64 + tx * 4;    // within [0,2048)
#pragma unroll
    for (int m = 0; m < 4; ++m) {
        const int gi = i0g + ty * 4 + m;
        float ov[4];
#pragma unroll
        for (int n = 0; n < 4; ++n) {
            float h = acc[m][n];
            if (second) h += b1[col + n];
            ov[n] = exp2f(C2LOG2E * h);   // cold path: 1M exps total, libm ok
        }
        float4 o;
        o.x = ov[0]; o.y = ov[1]; o.z = ov[2]; o.w = ov[3];
        *(float4*)&E[gi * 2048 + ecol] = o;
    }
}

// ---------------------------------------------------------------------------
// Kernel B: partial scores, h-split in two halves (blockIdx.z).
//   q_z[i][j] = (z==0? b2 : 0) + sum_{h in half} W2[h]
//               - 2 * sum_{h in half} W2[h] / (1 + E1[i][h]*E2[j][h])
// 32x32 output tile, 256 threads, 2x2 micro, 4-h vectorized inner loop.
// ---------------------------------------------------------------------------
#define T4(acc, ev, fv)                                                          \
    acc = __builtin_fmaf(w.x, rcp_fast(__builtin_fmaf(ev.x, fv.x, 1.0f)), acc);  \
    acc = __builtin_fmaf(w.y, rcp_fast(__builtin_fmaf(ev.y, fv.y, 1.0f)), acc);  \
    acc = __builtin_fmaf(w.z, rcp_fast(__builtin_fmaf(ev.z, fv.z, 1.0f)), acc);  \
    acc = __builtin_fmaf(w.w, rcp_fast(__builtin_fmaf(ev.w, fv.w, 1.0f)), acc);

__global__ __launch_bounds__(256) void k_score(const float* __restrict__ E,
                                               const float* __restrict__ W2,
                                               const float* __restrict__ b2,
                                               float* __restrict__ P) {
    __shared__ float e1s[32][132];   // [i][h], pad to 132 (16B-aligned rows)
    __shared__ float e2s[32][132];   // [j][h]
    __shared__ float w2s[128];
    const int t = threadIdx.x;
    const int i0g = blockIdx.x * 32;
    const int j0g = blockIdx.y * 32;
    const int z = blockIdx.z;
    const int hz = z * 512;
    const int tx = t & 15, ty = t >> 4;

    float a00 = 0.f, a01 = 0.f, a10 = 0.f, a11 = 0.f;
    float4 sw2v = make_float4(0.f, 0.f, 0.f, 0.f);

    for (int hc = 0; hc < 512; hc += 128) {
        const int hb = hz + hc;
#pragma unroll
        for (int u = 0; u < 16; ++u) {     // stage 32x128 of E1 and E2
            const int idx = t + u * 256;
            const int r = idx >> 7, h = idx & 127;
            e1s[r][h] = E[(i0g + r) * 2048 + hb + h];
            e2s[r][h] = E[(j0g + r) * 2048 + 1024 + hb + h];
        }
        if (t < 128) w2s[t] = W2[hb + t];
        __syncthreads();
#pragma unroll 4
        for (int hh = 0; hh < 128; hh += 4) {
            const float4 w  = *(const float4*)&w2s[hh];
            const float4 p  = *(const float4*)&e1s[ty * 2 + 0][hh];
            const float4 qq = *(const float4*)&e1s[ty * 2 + 1][hh];
            const float4 r0 = *(const float4*)&e2s[tx * 2 + 0][hh];
            const float4 r1 = *(const float4*)&e2s[tx * 2 + 1][hh];
            T4(a00, p,  r0)
            T4(a01, p,  r1)
            T4(a10, qq, r0)
            T4(a11, qq, r1)
            sw2v.x += w.x; sw2v.y += w.y; sw2v.z += w.z; sw2v.w += w.w;
        }
        __syncthreads();
    }

    const float sw2 = sw2v.x + sw2v.y + sw2v.z + sw2v.w;
    const float qbase = (z == 0 ? b2[0] : 0.0f) + sw2;
    float* __restrict__ Pz = P + z * NN * NN;
    const int gi0 = i0g + ty * 2;
    const int gj = j0g + tx * 2;
    float2 o0, o1;
    o0.x = qbase - 2.0f * a00; o0.y = qbase - 2.0f * a01;
    o1.x = qbase - 2.0f * a10; o1.y = qbase - 2.0f * a11;
    *(float2*)&Pz[gi0 * NN + gj] = o0;
    *(float2*)&Pz[(gi0 + 1) * NN + gj] = o1;
}

// ---------------------------------------------------------------------------
// Kernel C: out = q0 + q1
// ---------------------------------------------------------------------------
__global__ __launch_bounds__(256) void k_combine(const float* __restrict__ P,
                                                 float* __restrict__ out) {
    const int idx = blockIdx.x * 256 + threadIdx.x;   // 65536 float4s
    const float4* p0 = (const float4*)P;
    const float4* p1 = (const float4*)(P + NN * NN);
    const float4 a = p0[idx];
    const float4 b = p1[idx];
    float4 o;
    o.x = a.x + b.x; o.y = a.y + b.y; o.z = a.z + b.z; o.w = a.w + b.w;
    ((float4*)out)[idx] = o;
}

extern "C" void kernel_launch(void* const* d_in, const int* in_sizes, int n_in,
                              void* d_out, int out_size, void* d_ws, size_t ws_size,
                              hipStream_t stream) {
    const float* x  = (const float*)d_in[0];
    const float* W1 = (const float*)d_in[1];
    const float* b1 = (const float*)d_in[2];
    const float* W2 = (const float*)d_in[3];
    const float* b2 = (const float*)d_in[4];
    float* out = (float*)d_out;

    float* E = (float*)d_ws;                 // 512*2048 f32 = 4 MB
    float* P = E + NN * 2 * HH;              // 2 * 512*512 f32 = 2 MB

    k_gemm_exp<<<dim3(8, 32), 256, 0, stream>>>(x, W1, b1, E);
    k_score<<<dim3(16, 16, 2), 256, 0, stream>>>(E, W2, b2, P);
    k_combine<<<dim3(256), 256, 0, stream>>>(P, out);
}

// Round 2
// 58.275 us; speedup vs baseline: 1.2018x; 1.2018x over previous
//
#include <hip/hip_runtime.h>
#include <math.h>

#define NN 512
#define DD 512
#define HH 1024
#define C2LOG2E 2.8853900817779268f   // 2*log2(e): exp(2y) = exp2(C*y)

typedef __attribute__((ext_vector_type(8))) short bf16x8;
typedef __attribute__((ext_vector_type(4))) float f32x4;

static __device__ __forceinline__ float rcp_fast(float x) {
    return __builtin_amdgcn_rcpf(x);   // v_rcp_f32
}
static __device__ __forceinline__ ushort f2bf(float f) {   // RNE f32->bf16
    unsigned u = __float_as_uint(f);
    u += 0x7FFF + ((u >> 16) & 1);
    return (ushort)(u >> 16);
}

// ---------------------------------------------------------------------------
// Kernel 0: convert x -> xb (bf16 [512][512]) and W1 -> Bt (bf16 [2048][512],
// Bt[n][k] = W1[k + (n>=1024?512:0)][n%1024]) via LDS tile transpose.
// grid 512 blocks x 256 thr: bx<256 -> x convert, bx>=256 -> W1 transpose.
// ---------------------------------------------------------------------------
__global__ __launch_bounds__(256) void k_convert(const float* __restrict__ x,
                                                 const float* __restrict__ W1,
                                                 short* __restrict__ xb,
                                                 short* __restrict__ Bt) {
    __shared__ float ts[64][65];
    const int t = threadIdx.x;
    const int bx = blockIdx.x;
    if (bx < 256) {                        // x: 65536 float4s
        const int f4 = bx * 256 + t;
        const float4 v = *(const float4*)&x[f4 * 4];
        ushort4 o;
        o.x = f2bf(v.x); o.y = f2bf(v.y); o.z = f2bf(v.z); o.w = f2bf(v.w);
        *(ushort4*)&xb[f4 * 4] = o;
        return;
    }
    const int tid = bx - 256;              // 8 k-tiles x 32 n-tiles
    const int k0 = (tid >> 5) * 64;
    const int nglob = (tid & 31) * 64;
    const int off = (nglob >= 1024) ? 512 : 0;
    const int nm = nglob & 1023;
#pragma unroll
    for (int u = 0; u < 4; ++u) {          // load 64(k) x 64(n) f32
        const int f4 = t + u * 256;
        const int r = f4 >> 4, c = (f4 & 15) * 4;
        *(float4*)&ts[r][c] = *(const float4*)&W1[(off + k0 + r) * HH + nm + c];
    }
    __syncthreads();
#pragma unroll
    for (int u = 0; u < 4; ++u) {          // store transposed as bf16
        const int idx = t + u * 256;
        const int nn = idx >> 4, k4 = (idx & 15) * 4;
        ushort4 o;
        o.x = f2bf(ts[k4 + 0][nn]);
        o.y = f2bf(ts[k4 + 1][nn]);
        o.z = f2bf(ts[k4 + 2][nn]);
        o.w = f2bf(ts[k4 + 3][nn]);
        *(ushort4*)&Bt[(nglob + nn) * DD + k0 + k4] = o;
    }
}

// ---------------------------------------------------------------------------
// Kernel 1: E[i][n] = exp2(C*(h + (n>=1024? b1[n-1024] : 0))), h = (xb@Bt^T).
// LDS-free bf16 MFMA 16x16x32. Block 256 thr = 4 waves; wave w: rows
// [bx*64+w*16, +16) x cols [by*64, +64). grid (8, 32).
// ---------------------------------------------------------------------------
__global__ __launch_bounds__(256) void k_gemm_mfma(const short* __restrict__ xb,
                                                   const short* __restrict__ Bt,
                                                   const float* __restrict__ b1,
                                                   float* __restrict__ E) {
    const int t = threadIdx.x;
    const int w = t >> 6, l = t & 63;
    const int i0 = blockIdx.x * 64 + w * 16;
    const int n0 = blockIdx.y * 64;
    const int lm = l & 15;
    const int krow = (l >> 4) * 8;         // k offset within 32-step

    f32x4 acc[4] = {};
    const short* xp = xb + (i0 + lm) * DD + krow;
    const short* bp0 = Bt + (n0 + 0 * 16 + lm) * DD + krow;
    const short* bp1 = Bt + (n0 + 1 * 16 + lm) * DD + krow;
    const short* bp2 = Bt + (n0 + 2 * 16 + lm) * DD + krow;
    const short* bp3 = Bt + (n0 + 3 * 16 + lm) * DD + krow;
#pragma unroll
    for (int kt = 0; kt < DD; kt += 32) {
        const bf16x8 a = *(const bf16x8*)(xp + kt);
        acc[0] = __builtin_amdgcn_mfma_f32_16x16x32_bf16(a, *(const bf16x8*)(bp0 + kt), acc[0], 0, 0, 0);
        acc[1] = __builtin_amdgcn_mfma_f32_16x16x32_bf16(a, *(const bf16x8*)(bp1 + kt), acc[1], 0, 0, 0);
        acc[2] = __builtin_amdgcn_mfma_f32_16x16x32_bf16(a, *(const bf16x8*)(bp2 + kt), acc[2], 0, 0, 0);
        acc[3] = __builtin_amdgcn_mfma_f32_16x16x32_bf16(a, *(const bf16x8*)(bp3 + kt), acc[3], 0, 0, 0);
    }
    // C/D map: value (reg r, lane l) -> row (l>>4)*4+r, col l&15 (m89-verified)
    const int orow = i0 + (l >> 4) * 4;
#pragma unroll
    for (int c = 0; c < 4; ++c) {
        const int n = n0 + c * 16 + lm;
        const float badd = (n >= HH) ? b1[n - HH] : 0.0f;
#pragma unroll
        for (int r = 0; r < 4; ++r) {
            E[(orow + r) * (2 * HH) + n] = exp2f(C2LOG2E * (acc[c][r] + badd));
        }
    }
}

// ---------------------------------------------------------------------------
// Kernel 2: partial scores. z in [0,16) covers h-range [z*64, z*64+64).
// P_z[i][j] = sum_{h in z} W2[h] - 2*sum_{h in z} W2[h]/(1 + E1[i][h]*E2[j][h])
// 64x64 tile, 256 thr, 4x4 micro. i rows = ty*4+m, j cols = tx+16n
// (both conflict-free: 2-way max). grid (8, 8, 16).
// ---------------------------------------------------------------------------
__global__ __launch_bounds__(256) void k_score(const float* __restrict__ E,
                                               const float* __restrict__ W2,
                                               float* __restrict__ P) {
    __shared__ float e1s[64][68];
    __shared__ float e2s[64][68];
    __shared__ float w2s[64];
    const int t = threadIdx.x;
    const int i0 = blockIdx.x * 64, j0 = blockIdx.y * 64;
    const int z = blockIdx.z;
    const int hb = z * 64;
    const int tx = t & 15, ty = t >> 4;

#pragma unroll
    for (int u = 0; u < 4; ++u) {          // stage 64x64 of E1 and E2
        const int f4 = t + u * 256;
        const int r = f4 >> 4, c = (f4 & 15) * 4;
        *(float4*)&e1s[r][c] = *(const float4*)&E[(i0 + r) * (2 * HH) + hb + c];
        *(float4*)&e2s[r][c] = *(const float4*)&E[(j0 + r) * (2 * HH) + HH + hb + c];
    }
    if (t < 64) w2s[t] = W2[hb + t];
    __syncthreads();

    float acc[4][4] = {};
    float sw = 0.0f;
    const float* e1p = &e1s[ty * 4][0];
    const float* e2p = &e2s[tx][0];
#pragma unroll 4
    for (int hq = 0; hq < 16; ++hq) {
        const int h = hq * 4;
        const float4 w = *(const float4*)&w2s[h];
        float4 ev[4], fv[4];
#pragma unroll
        for (int m = 0; m < 4; ++m) ev[m] = *(const float4*)(e1p + m * 68 + h);
#pragma unroll
        for (int n = 0; n < 4; ++n) fv[n] = *(const float4*)(e2p + n * 16 * 68 + h);
#pragma unroll
        for (int m = 0; m < 4; ++m) {
#pragma unroll
            for (int n = 0; n < 4; ++n) {
                float a = acc[m][n];
                a = __builtin_fmaf(w.x, rcp_fast(__builtin_fmaf(ev[m].x, fv[n].x, 1.0f)), a);
                a = __builtin_fmaf(w.y, rcp_fast(__builtin_fmaf(ev[m].y, fv[n].y, 1.0f)), a);
                a = __builtin_fmaf(w.z, rcp_fast(__builtin_fmaf(ev[m].z, fv[n].z, 1.0f)), a);
                a = __builtin_fmaf(w.w, rcp_fast(__builtin_fmaf(ev[m].w, fv[n].w, 1.0f)), a);
                acc[m][n] = a;
            }
        }
        sw += w.x + w.y + w.z + w.w;
    }

    float* __restrict__ Pz = P + z * NN * NN;
#pragma unroll
    for (int m = 0; m < 4; ++m) {
        const int row = i0 + ty * 4 + m;
#pragma unroll
        for (int n = 0; n < 4; ++n) {
            const int col = j0 + tx + n * 16;
            Pz[row * NN + col] = sw - 2.0f * acc[m][n];
        }
    }
}

// ---------------------------------------------------------------------------
// Kernel 3: out = b2 + sum_z P_z
// ---------------------------------------------------------------------------
__global__ __launch_bounds__(256) void k_combine(const float* __restrict__ P,
                                                 const float* __restrict__ b2,
                                                 float* __restrict__ out) {
    const int idx = blockIdx.x * 256 + threadIdx.x;   // 65536 float4s
    float4 s = make_float4(0.f, 0.f, 0.f, 0.f);
#pragma unroll
    for (int z = 0; z < 16; ++z) {
        const float4 p = ((const float4*)(P + z * NN * NN))[idx];
        s.x += p.x; s.y += p.y; s.z += p.z; s.w += p.w;
    }
    const float b = b2[0];
    float4 o;
    o.x = s.x + b; o.y = s.y + b; o.z = s.z + b; o.w = s.w + b;
    ((float4*)out)[idx] = o;
}

extern "C" void kernel_launch(void* const* d_in, const int* in_sizes, int n_in,
                              void* d_out, int out_size, void* d_ws, size_t ws_size,
                              hipStream_t stream) {
    const float* x  = (const float*)d_in[0];
    const float* W1 = (const float*)d_in[1];
    const float* b1 = (const float*)d_in[2];
    const float* W2 = (const float*)d_in[3];
    const float* b2 = (const float*)d_in[4];
    float* out = (float*)d_out;

    float* E  = (float*)d_ws;                    // 512*2048 f32   = 4 MB
    float* P  = E + NN * 2 * HH;                 // 16 * 512*512   = 16 MB
    short* xb = (short*)(P + 16 * NN * NN);      // 512*512 bf16   = 0.5 MB
    short* Bt = xb + NN * DD;                    // 2048*512 bf16  = 2 MB

    k_convert<<<dim3(512), 256, 0, stream>>>(x, W1, xb, Bt);
    k_gemm_mfma<<<dim3(8, 32), 256, 0, stream>>>(xb, Bt, b1, E);
    k_score<<<dim3(8, 8, 16), 256, 0, stream>>>(E, W2, P);
    k_combine<<<dim3(256), 256, 0, stream>>>(P, b2, out);
}

// Round 3
// 53.038 us; speedup vs baseline: 1.3205x; 1.0987x over previous
//
#include <hip/hip_runtime.h>
#include <math.h>

#define NN 512
#define DD 512
#define HH 1024
#define C2LOG2E 2.8853900817779268f   // 2*log2(e): exp(2y) = exp2(C*y)

typedef __attribute__((ext_vector_type(8))) short bf16x8;
typedef __attribute__((ext_vector_type(4))) float f32x4;

static __device__ __forceinline__ float rcp_fast(float x) {
    return __builtin_amdgcn_rcpf(x);   // v_rcp_f32
}
static __device__ __forceinline__ ushort f2bf(float f) {   // RNE f32->bf16
    unsigned u = __float_as_uint(f);
    u += 0x7FFF + ((u >> 16) & 1);
    return (ushort)(u >> 16);
}

// ---------------------------------------------------------------------------
// Kernel 0: convert x -> xb (bf16 [512][512]) and W1 -> Bt (bf16 [2048][512],
// Bt[n][k] = W1[k + (n>=1024?512:0)][n%1024]) via LDS tile transpose.
// grid 512 blocks x 256 thr: bx<256 -> x convert, bx>=256 -> W1 transpose.
// ---------------------------------------------------------------------------
__global__ __launch_bounds__(256) void k_convert(const float* __restrict__ x,
                                                 const float* __restrict__ W1,
                                                 short* __restrict__ xb,
                                                 short* __restrict__ Bt) {
    __shared__ float ts[64][65];
    const int t = threadIdx.x;
    const int bx = blockIdx.x;
    if (bx < 256) {                        // x: 65536 float4s
        const int f4 = bx * 256 + t;
        const float4 v = *(const float4*)&x[f4 * 4];
        ushort4 o;
        o.x = f2bf(v.x); o.y = f2bf(v.y); o.z = f2bf(v.z); o.w = f2bf(v.w);
        *(ushort4*)&xb[f4 * 4] = o;
        return;
    }
    const int tid = bx - 256;              // 8 k-tiles x 32 n-tiles
    const int k0 = (tid >> 5) * 64;
    const int nglob = (tid & 31) * 64;
    const int off = (nglob >= 1024) ? 512 : 0;
    const int nm = nglob & 1023;
#pragma unroll
    for (int u = 0; u < 4; ++u) {          // load 64(k) x 64(n) f32
        const int f4 = t + u * 256;
        const int r = f4 >> 4, c = (f4 & 15) * 4;
        *(float4*)&ts[r][c] = *(const float4*)&W1[(off + k0 + r) * HH + nm + c];
    }
    __syncthreads();
#pragma unroll
    for (int u = 0; u < 4; ++u) {          // store transposed as bf16
        const int idx = t + u * 256;
        const int nn = idx >> 4, k4 = (idx & 15) * 4;
        ushort4 o;
        o.x = f2bf(ts[k4 + 0][nn]);
        o.y = f2bf(ts[k4 + 1][nn]);
        o.z = f2bf(ts[k4 + 2][nn]);
        o.w = f2bf(ts[k4 + 3][nn]);
        *(ushort4*)&Bt[(nglob + nn) * DD + k0 + k4] = o;
    }
}

// ---------------------------------------------------------------------------
// Kernel 1: E[i][n] = exp2(C*(h + (n>=1024? b1[n-1024] : 0))), h = (xb@Bt^T).
// LDS-free bf16 MFMA 16x16x32. Wave tile 16i x 32n (2 MFMA chains).
// Block 256 thr = 4 waves stacked in i (64i x 32n). grid (8, 64) = 512 blocks
// -> 2 blocks/CU = 2 waves/SIMD (was 1 — latency hiding was the bottleneck).
// ---------------------------------------------------------------------------
__global__ __launch_bounds__(256) void k_gemm_mfma(const short* __restrict__ xb,
                                                   const short* __restrict__ Bt,
                                                   const float* __restrict__ b1,
                                                   float* __restrict__ E) {
    const int t = threadIdx.x;
    const int w = t >> 6, l = t & 63;
    const int i0 = blockIdx.x * 64 + w * 16;
    const int n0 = blockIdx.y * 32;
    const int lm = l & 15;
    const int krow = (l >> 4) * 8;         // k offset within 32-step

    f32x4 acc[2] = {};
    const short* xp  = xb + (i0 + lm) * DD + krow;
    const short* bp0 = Bt + (n0 + 0 * 16 + lm) * DD + krow;
    const short* bp1 = Bt + (n0 + 1 * 16 + lm) * DD + krow;
#pragma unroll
    for (int kt = 0; kt < DD; kt += 32) {
        const bf16x8 a = *(const bf16x8*)(xp + kt);
        acc[0] = __builtin_amdgcn_mfma_f32_16x16x32_bf16(a, *(const bf16x8*)(bp0 + kt), acc[0], 0, 0, 0);
        acc[1] = __builtin_amdgcn_mfma_f32_16x16x32_bf16(a, *(const bf16x8*)(bp1 + kt), acc[1], 0, 0, 0);
    }
    // C/D map: (reg r, lane l) -> row (l>>4)*4+r, col l&15 (m89-verified)
    const int orow = i0 + (l >> 4) * 4;
#pragma unroll
    for (int c = 0; c < 2; ++c) {
        const int n = n0 + c * 16 + lm;
        const float badd = (n >= HH) ? b1[n - HH] : 0.0f;
#pragma unroll
        for (int r = 0; r < 4; ++r) {
            E[(orow + r) * (2 * HH) + n] = exp2f(C2LOG2E * (acc[c][r] + badd));
        }
    }
}

// ---------------------------------------------------------------------------
// Kernel 2: partial scores. z in [0,16) covers h-range [z*64, z*64+64).
// P_z[i][j] = sum_{h in z} W2[h] - 2*sum_{h in z} W2[h]/(1 + E1[i][h]*E2[j][h])
// 64x64 tile, 256 thr, 4x4 micro. 4-way fraction-tree combine: one v_rcp per
// 4 h-terms (9 wave-cyc/elem vs 12 with per-term rcp). grid (8, 8, 16).
// ---------------------------------------------------------------------------
__global__ __launch_bounds__(256) void k_score(const float* __restrict__ E,
                                               const float* __restrict__ W2,
                                               float* __restrict__ P) {
    __shared__ float e1s[64][68];
    __shared__ float e2s[64][68];
    __shared__ float w2s[64];
    const int t = threadIdx.x;
    const int i0 = blockIdx.x * 64, j0 = blockIdx.y * 64;
    const int z = blockIdx.z;
    const int hb = z * 64;
    const int tx = t & 15, ty = t >> 4;

#pragma unroll
    for (int u = 0; u < 4; ++u) {          // stage 64x64 of E1 and E2
        const int f4 = t + u * 256;
        const int r = f4 >> 4, c = (f4 & 15) * 4;
        *(float4*)&e1s[r][c] = *(const float4*)&E[(i0 + r) * (2 * HH) + hb + c];
        *(float4*)&e2s[r][c] = *(const float4*)&E[(j0 + r) * (2 * HH) + HH + hb + c];
    }
    if (t < 64) w2s[t] = W2[hb + t];
    __syncthreads();

    float acc[4][4] = {};
    float sw = 0.0f;
    const float* e1p = &e1s[ty * 4][0];
    const float* e2p = &e2s[tx][0];
#pragma unroll 4
    for (int hq = 0; hq < 16; ++hq) {
        const int h = hq * 4;
        const float4 w = *(const float4*)&w2s[h];
        float4 ev[4], fv[4];
#pragma unroll
        for (int m = 0; m < 4; ++m) ev[m] = *(const float4*)(e1p + m * 68 + h);
#pragma unroll
        for (int n = 0; n < 4; ++n) fv[n] = *(const float4*)(e2p + n * 16 * 68 + h);
#pragma unroll
        for (int m = 0; m < 4; ++m) {
#pragma unroll
            for (int n = 0; n < 4; ++n) {
                // S = w0/d0 + w1/d1 + w2/d2 + w3/d3  computed as N/D
                const float d0 = __builtin_fmaf(ev[m].x, fv[n].x, 1.0f);
                const float d1 = __builtin_fmaf(ev[m].y, fv[n].y, 1.0f);
                const float d2 = __builtin_fmaf(ev[m].z, fv[n].z, 1.0f);
                const float d3 = __builtin_fmaf(ev[m].w, fv[n].w, 1.0f);
                const float d01 = d0 * d1;
                const float d23 = d2 * d3;
                const float n01 = __builtin_fmaf(w.x, d1, w.y * d0);
                const float n23 = __builtin_fmaf(w.z, d3, w.w * d2);
                const float Nn  = __builtin_fmaf(n01, d23, n23 * d01);
                const float Dd  = d01 * d23;
                acc[m][n] = __builtin_fmaf(Nn, rcp_fast(Dd), acc[m][n]);
            }
        }
        sw += w.x + w.y + w.z + w.w;
    }

    float* __restrict__ Pz = P + z * NN * NN;
#pragma unroll
    for (int m = 0; m < 4; ++m) {
        const int row = i0 + ty * 4 + m;
#pragma unroll
        for (int n = 0; n < 4; ++n) {
            const int col = j0 + tx + n * 16;
            Pz[row * NN + col] = sw - 2.0f * acc[m][n];
        }
    }
}

// ---------------------------------------------------------------------------
// Kernel 3: out = b2 + sum_z P_z
// ---------------------------------------------------------------------------
__global__ __launch_bounds__(256) void k_combine(const float* __restrict__ P,
                                                 const float* __restrict__ b2,
                                                 float* __restrict__ out) {
    const int idx = blockIdx.x * 256 + threadIdx.x;   // 65536 float4s
    float4 s = make_float4(0.f, 0.f, 0.f, 0.f);
#pragma unroll
    for (int z = 0; z < 16; ++z) {
        const float4 p = ((const float4*)(P + z * NN * NN))[idx];
        s.x += p.x; s.y += p.y; s.z += p.z; s.w += p.w;
    }
    const float b = b2[0];
    float4 o;
    o.x = s.x + b; o.y = s.y + b; o.z = s.z + b; o.w = s.w + b;
    ((float4*)out)[idx] = o;
}

extern "C" void kernel_launch(void* const* d_in, const int* in_sizes, int n_in,
                              void* d_out, int out_size, void* d_ws, size_t ws_size,
                              hipStream_t stream) {
    const float* x  = (const float*)d_in[0];
    const float* W1 = (const float*)d_in[1];
    const float* b1 = (const float*)d_in[2];
    const float* W2 = (const float*)d_in[3];
    const float* b2 = (const float*)d_in[4];
    float* out = (float*)d_out;

    float* E  = (float*)d_ws;                    // 512*2048 f32   = 4 MB
    float* P  = E + NN * 2 * HH;                 // 16 * 512*512   = 16 MB
    short* xb = (short*)(P + 16 * NN * NN);      // 512*512 bf16   = 0.5 MB
    short* Bt = xb + NN * DD;                    // 2048*512 bf16  = 2 MB

    k_convert<<<dim3(512), 256, 0, stream>>>(x, W1, xb, Bt);
    k_gemm_mfma<<<dim3(8, 64), 256, 0, stream>>>(xb, Bt, b1, E);
    k_score<<<dim3(8, 8, 16), 256, 0, stream>>>(E, W2, P);
    k_combine<<<dim3(256), 256, 0, stream>>>(P, b2, out);
}

// Round 5
// 50.411 us; speedup vs baseline: 1.3893x; 1.0521x over previous
//
#include <hip/hip_runtime.h>
#include <math.h>

#define NN 512
#define DD 512
#define HH 1024
#define C2LOG2E 2.8853900817779268f   // 2*log2(e): exp(2y) = exp2(C*y)

typedef __attribute__((ext_vector_type(8))) short bf16x8;
typedef __attribute__((ext_vector_type(4))) float f32x4;

static __device__ __forceinline__ float rcp_fast(float x) {
    return __builtin_amdgcn_rcpf(x);   // v_rcp_f32
}
static __device__ __forceinline__ float exp2_fast(float x) {
    return __builtin_amdgcn_exp2f(x);  // v_exp_f32
}
static __device__ __forceinline__ ushort f2bf(float f) {   // RNE f32->bf16
    unsigned u = __float_as_uint(f);
    u += 0x7FFF + ((u >> 16) & 1);
    return (ushort)(u >> 16);
}

// ---------------------------------------------------------------------------
// Kernel 0 (grid 768):
//   bx <  256: x -> xb (bf16)
//   bx in [256,512): W1 -> Bt (bf16, transposed [n][k]) via LDS tile transpose
//   bx >= 512: out = b2 (init for k_score's atomic accumulation)
// ---------------------------------------------------------------------------
__global__ __launch_bounds__(256) void k_convert(const float* __restrict__ x,
                                                 const float* __restrict__ W1,
                                                 const float* __restrict__ b2,
                                                 short* __restrict__ xb,
                                                 short* __restrict__ Bt,
                                                 float* __restrict__ out) {
    __shared__ float ts[64][65];
    const int t = threadIdx.x;
    const int bx = blockIdx.x;
    if (bx < 256) {                        // x: 65536 float4s
        const int f4 = bx * 256 + t;
        const float4 v = *(const float4*)&x[f4 * 4];
        ushort4 o;
        o.x = f2bf(v.x); o.y = f2bf(v.y); o.z = f2bf(v.z); o.w = f2bf(v.w);
        *(ushort4*)&xb[f4 * 4] = o;
        return;
    }
    if (bx >= 512) {                       // out init: 65536 float4s
        const int f4 = (bx - 512) * 256 + t;
        const float b = b2[0];
        float4 o; o.x = b; o.y = b; o.z = b; o.w = b;
        ((float4*)out)[f4] = o;
        return;
    }
    const int tid = bx - 256;              // 8 k-tiles x 32 n-tiles
    const int k0 = (tid >> 5) * 64;
    const int nglob = (tid & 31) * 64;
    const int off = (nglob >= 1024) ? 512 : 0;
    const int nm = nglob & 1023;
#pragma unroll
    for (int u = 0; u < 4; ++u) {          // load 64(k) x 64(n) f32
        const int f4 = t + u * 256;
        const int r = f4 >> 4, c = (f4 & 15) * 4;
        *(float4*)&ts[r][c] = *(const float4*)&W1[(off + k0 + r) * HH + nm + c];
    }
    __syncthreads();
#pragma unroll
    for (int u = 0; u < 4; ++u) {          // store transposed as bf16
        const int idx = t + u * 256;
        const int nn = idx >> 4, k4 = (idx & 15) * 4;
        ushort4 o;
        o.x = f2bf(ts[k4 + 0][nn]);
        o.y = f2bf(ts[k4 + 1][nn]);
        o.z = f2bf(ts[k4 + 2][nn]);
        o.w = f2bf(ts[k4 + 3][nn]);
        *(ushort4*)&Bt[(nglob + nn) * DD + k0 + k4] = o;
    }
}

// ---------------------------------------------------------------------------
// Kernel 1: E[i][n] = exp2(C*(h + (n>=1024? b1[n-1024] : 0))), h = (xb@Bt^T).
// LDS-free bf16 MFMA 16x16x32. Wave tile 16i x 32n (2 MFMA chains).
// Block 256 thr = 4 waves stacked in i (64i x 32n). grid (8, 64) = 512 blocks.
// ---------------------------------------------------------------------------
__global__ __launch_bounds__(256) void k_gemm_mfma(const short* __restrict__ xb,
                                                   const short* __restrict__ Bt,
                                                   const float* __restrict__ b1,
                                                   float* __restrict__ E) {
    const int t = threadIdx.x;
    const int w = t >> 6, l = t & 63;
    const int i0 = blockIdx.x * 64 + w * 16;
    const int n0 = blockIdx.y * 32;
    const int lm = l & 15;
    const int krow = (l >> 4) * 8;         // k offset within 32-step

    f32x4 acc[2] = {};
    const short* xp  = xb + (i0 + lm) * DD + krow;
    const short* bp0 = Bt + (n0 + 0 * 16 + lm) * DD + krow;
    const short* bp1 = Bt + (n0 + 1 * 16 + lm) * DD + krow;
#pragma unroll
    for (int kt = 0; kt < DD; kt += 32) {
        const bf16x8 a = *(const bf16x8*)(xp + kt);
        acc[0] = __builtin_amdgcn_mfma_f32_16x16x32_bf16(a, *(const bf16x8*)(bp0 + kt), acc[0], 0, 0, 0);
        acc[1] = __builtin_amdgcn_mfma_f32_16x16x32_bf16(a, *(const bf16x8*)(bp1 + kt), acc[1], 0, 0, 0);
    }
    // C/D map: (reg r, lane l) -> row (l>>4)*4+r, col l&15 (m89-verified)
    const int orow = i0 + (l >> 4) * 4;
#pragma unroll
    for (int c = 0; c < 2; ++c) {
        const int n = n0 + c * 16 + lm;
        const float badd = (n >= HH) ? b1[n - HH] : 0.0f;
#pragma unroll
        for (int r = 0; r < 4; ++r) {
            E[(orow + r) * (2 * HH) + n] = exp2_fast(C2LOG2E * (acc[c][r] + badd));
        }
    }
}

// ---------------------------------------------------------------------------
// Kernel 2: partial scores, atomically accumulated into out.
// z in [0,16) covers h-range [z*64, z*64+64).
// out[i][j] += sum_{h in z} W2[h] - 2*sum_{h in z} W2[h]/(1 + E1[i][h]*E2[j][h])
// 64x64 tile, 256 thr, 4x4 micro. 4-way fraction tree: one v_rcp per 4 h.
// grid (8, 8, 16) = 1024 blocks = 4/CU = 4 waves/SIMD.
// ---------------------------------------------------------------------------
__global__ __launch_bounds__(256) void k_score(const float* __restrict__ E,
                                               const float* __restrict__ W2,
                                               float* __restrict__ out) {
    __shared__ float e1s[64][68];
    __shared__ float e2s[64][68];
    __shared__ float w2s[64];
    const int t = threadIdx.x;
    const int i0 = blockIdx.x * 64, j0 = blockIdx.y * 64;
    const int z = blockIdx.z;
    const int hb = z * 64;
    const int tx = t & 15, ty = t >> 4;

#pragma unroll
    for (int u = 0; u < 4; ++u) {          // stage 64x64 of E1 and E2
        const int f4 = t + u * 256;
        const int r = f4 >> 4, c = (f4 & 15) * 4;
        *(float4*)&e1s[r][c] = *(const float4*)&E[(i0 + r) * (2 * HH) + hb + c];
        *(float4*)&e2s[r][c] = *(const float4*)&E[(j0 + r) * (2 * HH) + HH + hb + c];
    }
    if (t < 64) w2s[t] = W2[hb + t];
    __syncthreads();

    float acc[4][4] = {};
    float sw = 0.0f;
    const float* e1p = &e1s[ty * 4][0];
    const float* e2p = &e2s[tx][0];
#pragma unroll 4
    for (int hq = 0; hq < 16; ++hq) {
        const int h = hq * 4;
        const float4 w = *(const float4*)&w2s[h];
        float4 ev[4], fv[4];
#pragma unroll
        for (int m = 0; m < 4; ++m) ev[m] = *(const float4*)(e1p + m * 68 + h);
#pragma unroll
        for (int n = 0; n < 4; ++n) fv[n] = *(const float4*)(e2p + n * 16 * 68 + h);
#pragma unroll
        for (int m = 0; m < 4; ++m) {
#pragma unroll
            for (int n = 0; n < 4; ++n) {
                // S = w0/d0 + w1/d1 + w2/d2 + w3/d3  computed as N/D
                const float d0 = __builtin_fmaf(ev[m].x, fv[n].x, 1.0f);
                const float d1 = __builtin_fmaf(ev[m].y, fv[n].y, 1.0f);
                const float d2 = __builtin_fmaf(ev[m].z, fv[n].z, 1.0f);
                const float d3 = __builtin_fmaf(ev[m].w, fv[n].w, 1.0f);
                const float d01 = d0 * d1;
                const float d23 = d2 * d3;
                const float n01 = __builtin_fmaf(w.x, d1, w.y * d0);
                const float n23 = __builtin_fmaf(w.z, d3, w.w * d2);
                const float Nn  = __builtin_fmaf(n01, d23, n23 * d01);
                const float Dd  = d01 * d23;
                acc[m][n] = __builtin_fmaf(Nn, rcp_fast(Dd), acc[m][n]);
            }
        }
        sw += w.x + w.y + w.z + w.w;
    }

#pragma unroll
    for (int m = 0; m < 4; ++m) {
        const int row = i0 + ty * 4 + m;
#pragma unroll
        for (int n = 0; n < 4; ++n) {
            const int col = j0 + tx + n * 16;
            atomicAdd(&out[row * NN + col], sw - 2.0f * acc[m][n]);
        }
    }
}

extern "C" void kernel_launch(void* const* d_in, const int* in_sizes, int n_in,
                              void* d_out, int out_size, void* d_ws, size_t ws_size,
                              hipStream_t stream) {
    const float* x  = (const float*)d_in[0];
    const float* W1 = (const float*)d_in[1];
    const float* b1 = (const float*)d_in[2];
    const float* W2 = (const float*)d_in[3];
    const float* b2 = (const float*)d_in[4];
    float* out = (float*)d_out;

    float* E  = (float*)d_ws;                    // 512*2048 f32   = 4 MB
    short* xb = (short*)(E + NN * 2 * HH);       // 512*512 bf16   = 0.5 MB
    short* Bt = xb + NN * DD;                    // 2048*512 bf16  = 2 MB

    k_convert<<<dim3(768), 256, 0, stream>>>(x, W1, b2, xb, Bt, out);
    k_gemm_mfma<<<dim3(8, 64), 256, 0, stream>>>(xb, Bt, b1, E);
    k_score<<<dim3(8, 8, 16), 256, 0, stream>>>(E, W2, out);
}

// Round 6
// 43.128 us; speedup vs baseline: 1.6240x; 1.1689x over previous
//
#include <hip/hip_runtime.h>
#include <math.h>

#define NN 512
#define DD 512
#define HH 1024
#define C2LOG2E 2.8853900817779268f   // 2*log2(e): exp(2y) = exp2(C*y)

typedef __attribute__((ext_vector_type(8))) short bf16x8;
typedef __attribute__((ext_vector_type(4))) float f32x4;

static __device__ __forceinline__ float rcp_fast(float x) {
    return __builtin_amdgcn_rcpf(x);   // v_rcp_f32
}
static __device__ __forceinline__ float exp2_fast(float x) {
    return __builtin_amdgcn_exp2f(x);  // v_exp_f32
}
static __device__ __forceinline__ ushort f2bf(float f) {   // RNE f32->bf16
    unsigned u = __float_as_uint(f);
    u += 0x7FFF + ((u >> 16) & 1);
    return (ushort)(u >> 16);
}
static __device__ __forceinline__ float bf2f(short u) {    // bf16->f32: 1 shl
    return __uint_as_float(((unsigned)(ushort)u) << 16);
}

// ---------------------------------------------------------------------------
// Kernel 0 (grid 640):
//   bx <  128: x -> xbs, bf16 PRE-SWIZZLED in MFMA A-fragment order:
//              elem(i,k) at ((i/16)*16 + k/32)*512 + ((k>>3)&3)*128 + (i&15)*8 + (k&7)
//   bx in [128,384): W1 -> Bts, bf16 fragment order over n-rows (same pattern)
//   bx >= 384: out = b2 (init for k_score's atomic accumulation)
// ---------------------------------------------------------------------------
__global__ __launch_bounds__(256) void k_convert(const float* __restrict__ x,
                                                 const float* __restrict__ W1,
                                                 const float* __restrict__ b2,
                                                 short* __restrict__ xbs,
                                                 short* __restrict__ Bts,
                                                 float* __restrict__ out) {
    __shared__ float ts[64][65];
    const int t = threadIdx.x;
    const int bx = blockIdx.x;
    if (bx < 128) {                        // xb swizzle: 32768 short8 chunks
        const int q = bx * 256 + t;
        const int g = q >> 10, ktc = (q >> 6) & 15, l = q & 63;
        const int i = g * 16 + (l & 15);
        const int k0 = ktc * 32 + (l >> 4) * 8;
        const float4 v0 = *(const float4*)&x[i * DD + k0];
        const float4 v1 = *(const float4*)&x[i * DD + k0 + 4];
        bf16x8 o;
        o[0] = (short)f2bf(v0.x); o[1] = (short)f2bf(v0.y);
        o[2] = (short)f2bf(v0.z); o[3] = (short)f2bf(v0.w);
        o[4] = (short)f2bf(v1.x); o[5] = (short)f2bf(v1.y);
        o[6] = (short)f2bf(v1.z); o[7] = (short)f2bf(v1.w);
        *(bf16x8*)&xbs[q * 8] = o;
        return;
    }
    if (bx >= 384) {                       // out init: 65536 float4s
        const int f4 = (bx - 384) * 256 + t;
        const float b = b2[0];
        float4 o; o.x = b; o.y = b; o.z = b; o.w = b;
        ((float4*)out)[f4] = o;
        return;
    }
    const int tid = bx - 128;              // 8 k-tiles x 32 n-tiles
    const int k0 = (tid >> 5) * 64;
    const int nglob = (tid & 31) * 64;
    const int off = (nglob >= 1024) ? 512 : 0;
    const int nm = nglob & 1023;
#pragma unroll
    for (int u = 0; u < 4; ++u) {          // load 64(k) x 64(n) f32
        const int f4 = t + u * 256;
        const int r = f4 >> 4, c = (f4 & 15) * 4;
        *(float4*)&ts[r][c] = *(const float4*)&W1[(off + k0 + r) * HH + nm + c];
    }
    __syncthreads();
#pragma unroll
    for (int u = 0; u < 2; ++u) {          // 512 output chunks, frag order
        const int q = u * 256 + t;
        const int lg = q >> 7, lc = (q >> 6) & 1, l = q & 63;
        const int n_loc = lg * 16 + (l & 15);
        const int k_loc = lc * 32 + (l >> 4) * 8;
        bf16x8 o;
#pragma unroll
        for (int j = 0; j < 8; ++j) o[j] = (short)f2bf(ts[k_loc + j][n_loc]);
        const int gg = (nglob >> 4) + lg;
        const int ktc = (k0 >> 5) + lc;
        *(bf16x8*)&Bts[((gg * 16 + ktc) * 64 + l) * 8] = o;
    }
}

// ---------------------------------------------------------------------------
// Kernel 1: Ebf[i][n] (bf16) = exp2(C*(h + (n>=1024? b1[n-1024] : 0))).
// Fragment-order inputs -> every load is base + lane*16B + ktc*1KB (coalesced).
// Wave tile 16i x 32n, block = 4 waves in i. grid (8, 64) = 512 blocks.
// ---------------------------------------------------------------------------
__global__ __launch_bounds__(256) void k_gemm_mfma(const short* __restrict__ xbs,
                                                   const short* __restrict__ Bts,
                                                   const float* __restrict__ b1,
                                                   short* __restrict__ Ebf) {
    const int t = threadIdx.x;
    const int w = t >> 6, l = t & 63;
    const int gi = blockIdx.x * 4 + w;     // i-group (16 rows)
    const int by = blockIdx.y;
    const int gn0 = by * 2;                // two n-groups of 16

    f32x4 acc[2] = {};
    const short* ap  = xbs + gi * 8192 + l * 8;
    const short* bp0 = Bts + (gn0 + 0) * 8192 + l * 8;
    const short* bp1 = Bts + (gn0 + 1) * 8192 + l * 8;
#pragma unroll
    for (int ktc = 0; ktc < 16; ++ktc) {
        const bf16x8 a = *(const bf16x8*)(ap + ktc * 512);
        acc[0] = __builtin_amdgcn_mfma_f32_16x16x32_bf16(a, *(const bf16x8*)(bp0 + ktc * 512), acc[0], 0, 0, 0);
        acc[1] = __builtin_amdgcn_mfma_f32_16x16x32_bf16(a, *(const bf16x8*)(bp1 + ktc * 512), acc[1], 0, 0, 0);
    }
    // C/D map: (reg r, lane l) -> row (l>>4)*4+r, col l&15 (m89-verified)
    const int lm = l & 15;
    const int orow = gi * 16 + (l >> 4) * 4;
    const bool second = (by >= 32);
#pragma unroll
    for (int c = 0; c < 2; ++c) {
        const int n = by * 32 + c * 16 + lm;
        const float badd = second ? b1[n - HH] : 0.0f;
#pragma unroll
        for (int r = 0; r < 4; ++r) {
            Ebf[(orow + r) * (2 * HH) + n] =
                (short)f2bf(exp2_fast(C2LOG2E * (acc[c][r] + badd)));
        }
    }
}

// ---------------------------------------------------------------------------
// Kernel 2: partial scores, atomically accumulated into out.
// z in [0,16): h-range [z*64, +64). bf16 LDS tiles (18 KB -> 8 blocks/CU).
// out[i][j] += sum_h W2[h] - 2*sum_h W2[h]/(1 + E1[i][h]*E2[j][h])
// 64x64 tile, 256 thr, 4x4 micro, 8-h steps (two 4-way fraction trees).
// ---------------------------------------------------------------------------
__global__ __launch_bounds__(256) void k_score(const short* __restrict__ Ebf,
                                               const float* __restrict__ W2,
                                               float* __restrict__ out) {
    __shared__ short e1s[64][72];   // row stride 144 B (16B-aligned)
    __shared__ short e2s[64][72];
    __shared__ float w2s[64];
    const int t = threadIdx.x;
    const int i0 = blockIdx.x * 64, j0 = blockIdx.y * 64;
    const int hb = blockIdx.z * 64;
    const int tx = t & 15, ty = t >> 4;

#pragma unroll
    for (int u = 0; u < 2; ++u) {          // stage 64x64 bf16 of E1 and E2
        const int q = u * 256 + t;
        const int r = q >> 3, c8 = (q & 7) * 8;
        *(bf16x8*)&e1s[r][c8] = *(const bf16x8*)&Ebf[(i0 + r) * (2 * HH) + hb + c8];
        *(bf16x8*)&e2s[r][c8] = *(const bf16x8*)&Ebf[(j0 + r) * (2 * HH) + HH + hb + c8];
    }
    if (t < 64) w2s[t] = W2[hb + t];
    __syncthreads();

    float acc[4][4] = {};
    float sw = 0.0f;
    const int ty4 = ty * 4;
#pragma unroll 2
    for (int hq = 0; hq < 64; hq += 8) {
        float ef[4][8], ff[4][8];
#pragma unroll
        for (int m = 0; m < 4; ++m) {
            const bf16x8 v = *(const bf16x8*)&e1s[ty4 + m][hq];
#pragma unroll
            for (int j = 0; j < 8; ++j) ef[m][j] = bf2f(v[j]);
        }
#pragma unroll
        for (int n = 0; n < 4; ++n) {
            const bf16x8 v = *(const bf16x8*)&e2s[tx + n * 16][hq];
#pragma unroll
            for (int j = 0; j < 8; ++j) ff[n][j] = bf2f(v[j]);
        }
        const float4 wl = *(const float4*)&w2s[hq];
        const float4 wh = *(const float4*)&w2s[hq + 4];
#pragma unroll
        for (int m = 0; m < 4; ++m) {
#pragma unroll
            for (int n = 0; n < 4; ++n) {
                const float* em = ef[m];
                const float* fn = ff[n];
                const float d0 = __builtin_fmaf(em[0], fn[0], 1.0f);
                const float d1 = __builtin_fmaf(em[1], fn[1], 1.0f);
                const float d2 = __builtin_fmaf(em[2], fn[2], 1.0f);
                const float d3 = __builtin_fmaf(em[3], fn[3], 1.0f);
                const float d4 = __builtin_fmaf(em[4], fn[4], 1.0f);
                const float d5 = __builtin_fmaf(em[5], fn[5], 1.0f);
                const float d6 = __builtin_fmaf(em[6], fn[6], 1.0f);
                const float d7 = __builtin_fmaf(em[7], fn[7], 1.0f);
                const float d01 = d0 * d1, d23 = d2 * d3;
                const float d45 = d4 * d5, d67 = d6 * d7;
                const float n01 = __builtin_fmaf(wl.x, d1, wl.y * d0);
                const float n23 = __builtin_fmaf(wl.z, d3, wl.w * d2);
                const float n45 = __builtin_fmaf(wh.x, d5, wh.y * d4);
                const float n67 = __builtin_fmaf(wh.z, d7, wh.w * d6);
                const float N1 = __builtin_fmaf(n01, d23, n23 * d01);
                const float N2 = __builtin_fmaf(n45, d67, n67 * d45);
                const float D1 = d01 * d23, D2 = d45 * d67;
                float a = acc[m][n];
                a = __builtin_fmaf(N1, rcp_fast(D1), a);
                a = __builtin_fmaf(N2, rcp_fast(D2), a);
                acc[m][n] = a;
            }
        }
        sw += wl.x + wl.y + wl.z + wl.w + wh.x + wh.y + wh.z + wh.w;
    }

#pragma unroll
    for (int m = 0; m < 4; ++m) {
        const int row = i0 + ty4 + m;
#pragma unroll
        for (int n = 0; n < 4; ++n) {
            const int col = j0 + tx + n * 16;
            atomicAdd(&out[row * NN + col], sw - 2.0f * acc[m][n]);
        }
    }
}

extern "C" void kernel_launch(void* const* d_in, const int* in_sizes, int n_in,
                              void* d_out, int out_size, void* d_ws, size_t ws_size,
                              hipStream_t stream) {
    const float* x  = (const float*)d_in[0];
    const float* W1 = (const float*)d_in[1];
    const float* b1 = (const float*)d_in[2];
    const float* W2 = (const float*)d_in[3];
    const float* b2 = (const float*)d_in[4];
    float* out = (float*)d_out;

    short* Ebf = (short*)d_ws;                   // 512*2048 bf16 = 2 MB
    short* xbs = Ebf + NN * 2 * HH;              // 512*512 bf16  = 0.5 MB
    short* Bts = xbs + NN * DD;                  // 2048*512 bf16 = 2 MB

    k_convert<<<dim3(640), 256, 0, stream>>>(x, W1, b2, xbs, Bts, out);
    k_gemm_mfma<<<dim3(8, 64), 256, 0, stream>>>(xbs, Bts, b1, Ebf);
    k_score<<<dim3(8, 8, 16), 256, 0, stream>>>(Ebf, W2, out);
}